// Round 4
// baseline (177.424 us; speedup 1.0000x reference)
//
#include <hip/hip_runtime.h>
#include <hip/hip_fp16.h>
#include <stdint.h>

#define NROWS 4096
#define DIM   512
#define BK    32
#define TILE  64
#define NBLK  64            // NROWS / TILE
#define NPAIR 2080          // NBLK*(NBLK+1)/2
#define KT    16            // DIM / BK

typedef float    f32x4 __attribute__((ext_vector_type(4)));
typedef _Float16 f16x8 __attribute__((ext_vector_type(8)));

// workspace layout (bytes)
#define OFF_XH   0u
#define OFF_SQ   (NROWS * DIM * 2u)          // 4,194,304
#define OFF_LAB  (OFF_SQ + NROWS * 4u)
#define OFF_ACC  (OFF_LAB + NROWS * 4u)      // [double s1][double s2][uint cnt][uint done][pad]

typedef __attribute__((address_space(1))) unsigned int glb_uint;
typedef __attribute__((address_space(3))) unsigned int lds_uint;

__device__ __forceinline__ void gl2lds16(const void* g, void* l) {
  __builtin_amdgcn_global_load_lds(
      (glb_uint*)(uintptr_t)g,
      (lds_uint*)(unsigned int)(uintptr_t)l,
      16, 0, 0);
}

// ---------------- prep: fp32 -> fp16, sq rows (fp32 exact), labels -> i32, zero accum
__global__ __launch_bounds__(256) void prep_kernel(
    const float* __restrict__ X, const long long* __restrict__ lab,
    unsigned short* __restrict__ Xh, float* __restrict__ sq,
    int* __restrict__ labi, unsigned* __restrict__ accum)
{
  int t = threadIdx.x;
  int gid = blockIdx.x * 256 + t;
  if (gid < 8) accum[gid] = 0u;                 // zero doubles + counters
  if (gid < NROWS) labi[gid] = (int)lab[gid];

  int wave = t >> 6, lane = t & 63;
  int row = blockIdx.x * 4 + wave;              // 1024 blocks * 4 rows
  const float4* Xr = (const float4*)(X + (size_t)row * DIM);
  float4 a = Xr[lane * 2];
  float4 b = Xr[lane * 2 + 1];

  uint4 pk;
  pk.x = (unsigned)__half_as_ushort(__float2half(a.x)) | ((unsigned)__half_as_ushort(__float2half(a.y)) << 16);
  pk.y = (unsigned)__half_as_ushort(__float2half(a.z)) | ((unsigned)__half_as_ushort(__float2half(a.w)) << 16);
  pk.z = (unsigned)__half_as_ushort(__float2half(b.x)) | ((unsigned)__half_as_ushort(__float2half(b.y)) << 16);
  pk.w = (unsigned)__half_as_ushort(__float2half(b.z)) | ((unsigned)__half_as_ushort(__float2half(b.w)) << 16);
  *(uint4*)(Xh + (size_t)row * DIM + lane * 8) = pk;

  float s = a.x*a.x + a.y*a.y + a.z*a.z + a.w*a.w
          + b.x*b.x + b.y*b.y + b.z*b.z + b.w*b.w;
  #pragma unroll
  for (int off = 32; off; off >>= 1) s += __shfl_down(s, off, 64);
  if (lane == 0) sq[row] = s;
}

// ---------------- main: 64x64 symmetric tiles, dbuf LDS pipeline, high occupancy
__global__ __launch_bounds__(256, 8) void pair_kernel(
    const unsigned short* __restrict__ Xh, const float* __restrict__ sq,
    const int* __restrict__ labi, const float* __restrict__ marginp,
    void* __restrict__ accumv, float* __restrict__ out)
{
  __shared__ unsigned short As[2][TILE * BK];   // 2 x 4 KB, XOR-swizzled k-groups
  __shared__ unsigned short Bs[2][TILE * BK];   // 2 x 4 KB
  __shared__ float sRow[TILE], sCol[TILE];
  __shared__ int   lRow[TILE], lCol[TILE];
  __shared__ float rs1[4], rs2[4];
  __shared__ int   rc[4];

  double*   accd = (double*)accumv;
  unsigned* accu = (unsigned*)accumv;           // [4]=cnt, [5]=done

  int t = threadIdx.x;

  // linear block -> (bi, bj) with bi <= bj
  int rem = blockIdx.x, bi = 0;
  while (rem >= (NBLK - bi)) { rem -= (NBLK - bi); bi++; }
  int bj = bi + rem;

  // epilogue metadata -> LDS (visible after the loop's first barrier)
  if (t < TILE) {
    sRow[t] = sq[bi * TILE + t];
    lRow[t] = labi[bi * TILE + t];
  } else if (t < 2 * TILE) {
    int u = t - TILE;
    sCol[u] = sq[bj * TILE + u];
    lCol[u] = labi[bj * TILE + u];
  }

  int wave = t >> 6, lane = t & 63;
  int quad = lane >> 4, ml = lane & 15;
  int waveRow = (wave >> 1) * 32, waveCol = (wave & 1) * 32;

  f32x4 acc[2][2] = {};

  // staging: thread t loads XOR-permuted k-group g of row r0 so that LDS slot
  // (t&3) of row (t>>2) holds global k-group g = (t&3) ^ ((t>>3)&3).
  const int r0 = t >> 2;                        // 0..63
  const int g  = (t & 3) ^ ((t >> 3) & 3);
  const size_t gA = (size_t)(bi * TILE + r0) * DIM + g * 8;
  const size_t gB = (size_t)(bj * TILE + r0) * DIM + g * 8;
  const int ldst = t * 8;                       // elems; wave-contiguous dest

  // read-side swizzled slot: (row>>1)&3 reduces to (ml>>1)&3 (waveRow,r*16 are 0 mod 32/16)
  const int slot = quad ^ ((ml >> 1) & 3);

  // prologue: stage k-tile 0 into buffer 0
  gl2lds16(Xh + gA, (void*)(As[0] + ldst));
  gl2lds16(Xh + gB, (void*)(Bs[0] + ldst));

  for (int kt = 0; kt < KT; ++kt) {
    int cur = kt & 1;
    __syncthreads();   // drains prefetch (vmcnt) + protects buffer reuse

    if (kt + 1 < KT) {
      size_t ko = (size_t)(kt + 1) * BK;
      gl2lds16(Xh + gA + ko, (void*)(As[cur ^ 1] + ldst));
      gl2lds16(Xh + gB + ko, (void*)(Bs[cur ^ 1] + ldst));
    }

    const f16x8* Ap = (const f16x8*)As[cur];
    const f16x8* Bp = (const f16x8*)Bs[cur];
    f16x8 af[2], bf[2];
    #pragma unroll
    for (int r = 0; r < 2; ++r)
      af[r] = Ap[(waveRow + r * 16 + ml) * 4 + slot];
    #pragma unroll
    for (int c = 0; c < 2; ++c)
      bf[c] = Bp[(waveCol + c * 16 + ml) * 4 + slot];

    #pragma unroll
    for (int r = 0; r < 2; ++r)
      #pragma unroll
      for (int c = 0; c < 2; ++c)
        acc[r][c] = __builtin_amdgcn_mfma_f32_16x16x32_f16(af[r], bf[c], acc[r][c], 0, 0, 0);
  }

  // ---- fused loss epilogue (32x32 quadrant per wave)
  float margin = *marginp;
  float s1 = 0.f, s2 = 0.f;
  int cnt = 0;
  #pragma unroll
  for (int c = 0; c < 2; ++c) {
    int col = waveCol + c * 16 + ml;
    float sqc = sCol[col];
    int lc = lCol[col];
    #pragma unroll
    for (int r = 0; r < 2; ++r) {
      int rbase = waveRow + r * 16 + quad * 4;   // C/D: row=(lane>>4)*4+reg, col=lane&15
      #pragma unroll
      for (int i = 0; i < 4; ++i) {
        int row = rbase + i;
        float d = sRow[row] + sqc - 2.0f * acc[r][c][i];
        d = fmaxf(d, 0.0f);
        if (lRow[row] == lc) { s1 += d; cnt++; }
        else                 { s2 += fmaxf(margin - d, 0.0f); }
      }
    }
  }

  #pragma unroll
  for (int off = 32; off; off >>= 1) {
    s1  += __shfl_down(s1, off, 64);
    s2  += __shfl_down(s2, off, 64);
    cnt += __shfl_down(cnt, off, 64);
  }
  if (lane == 0) { rs1[wave] = s1; rs2[wave] = s2; rc[wave] = cnt; }
  __syncthreads();
  if (t == 0) {
    double f = (bi == bj) ? 1.0 : 2.0;
    double S1 = 0.0, S2 = 0.0;
    int C = 0;
    for (int w = 0; w < 4; ++w) { S1 += (double)rs1[w]; S2 += (double)rs2[w]; C += rc[w]; }
    atomicAdd(&accd[0], S1 * f);
    atomicAdd(&accd[1], S2 * f);
    atomicAdd(&accu[4], (unsigned)C * (unsigned)((bi == bj) ? 1 : 2));
    __threadfence();
    unsigned prev = atomicAdd(&accu[5], 1u);
    if (prev == NPAIR - 1) {
      // last block: coherent readback via atomic RMW, then finalize
      double s1v = atomicAdd(&accd[0], 0.0);
      double s2v = atomicAdd(&accd[1], 0.0);
      unsigned c1 = atomicAdd(&accu[4], 0u);
      double zn1 = (double)c1;
      double zn2 = (double)NROWS * (double)NROWS - zn1;
      out[0] = (float)(0.5 * (s1v / zn1 + s2v / zn2));
    }
  }
}

extern "C" void kernel_launch(void* const* d_in, const int* in_sizes, int n_in,
                              void* d_out, int out_size, void* d_ws, size_t ws_size,
                              hipStream_t stream) {
  const float*     X      = (const float*)d_in[0];
  const long long* lab    = (const long long*)d_in[1];
  const float*     margin = (const float*)d_in[2];
  float*           out    = (float*)d_out;

  char* ws = (char*)d_ws;
  unsigned short* Xh   = (unsigned short*)(ws + OFF_XH);
  float*          sq   = (float*)(ws + OFF_SQ);
  int*            labi = (int*)(ws + OFF_LAB);
  unsigned*       accum= (unsigned*)(ws + OFF_ACC);

  prep_kernel<<<NROWS / 4, 256, 0, stream>>>(X, lab, Xh, sq, labi, accum);
  pair_kernel<<<NPAIR, 256, 0, stream>>>(Xh, sq, labi, margin, (void*)accum, out);
}

// Round 5
// 133.228 us; speedup vs baseline: 1.3317x; 1.3317x over previous
//
#include <hip/hip_runtime.h>
#include <hip/hip_fp16.h>
#include <stdint.h>

#define NROWS 4096
#define DIM   512
#define SLAB  64            // rows per block
#define CHUNK 512           // cols per block
#define NJT   (CHUNK / 16)  // 32 j-tiles per block, interleaved over 4 waves
#define GRID  ((NROWS / SLAB) * (NROWS / CHUNK))   // 64 * 8 = 512 blocks = 2/CU
#define ROWB  1040          // LDS row stride bytes (512*2 + 16 pad -> 2-way free)

typedef float    f32x4 __attribute__((ext_vector_type(4)));
typedef _Float16 f16x8 __attribute__((ext_vector_type(8)));

// workspace layout (bytes)
#define OFF_XH   0u
#define OFF_SQ   (NROWS * DIM * 2u)          // 4,194,304
#define OFF_LAB  (OFF_SQ + NROWS * 4u)
#define OFF_ACC  (OFF_LAB + NROWS * 4u)      // [f s1][f s2][u cnt][u done]

// ---------------- prep: fp32 -> fp16, sq rows (fp32 exact), labels -> i32, zero accum
__global__ __launch_bounds__(256) void prep_kernel(
    const float* __restrict__ X, const long long* __restrict__ lab,
    unsigned short* __restrict__ Xh, float* __restrict__ sq,
    int* __restrict__ labi, unsigned* __restrict__ accum)
{
  int t = threadIdx.x;
  int gid = blockIdx.x * 256 + t;
  if (gid < 4) accum[gid] = 0u;
  if (gid < NROWS) labi[gid] = (int)lab[gid];

  int wave = t >> 6, lane = t & 63;
  int row = blockIdx.x * 4 + wave;              // 1024 blocks * 4 rows
  const float4* Xr = (const float4*)(X + (size_t)row * DIM);
  float4 a = Xr[lane * 2];
  float4 b = Xr[lane * 2 + 1];

  uint4 pk;
  pk.x = (unsigned)__half_as_ushort(__float2half(a.x)) | ((unsigned)__half_as_ushort(__float2half(a.y)) << 16);
  pk.y = (unsigned)__half_as_ushort(__float2half(a.z)) | ((unsigned)__half_as_ushort(__float2half(a.w)) << 16);
  pk.z = (unsigned)__half_as_ushort(__float2half(b.x)) | ((unsigned)__half_as_ushort(__float2half(b.y)) << 16);
  pk.w = (unsigned)__half_as_ushort(__float2half(b.z)) | ((unsigned)__half_as_ushort(__float2half(b.w)) << 16);
  *(uint4*)(Xh + (size_t)row * DIM + lane * 8) = pk;

  float s = a.x*a.x + a.y*a.y + a.z*a.z + a.w*a.w
          + b.x*b.x + b.y*b.y + b.z*b.z + b.w*b.w;
  #pragma unroll
  for (int off = 32; off; off >>= 1) s += __shfl_down(s, off, 64);
  if (lane == 0) sq[row] = s;
}

// ---------------- main: 64-row slab in LDS, barrier-free streaming over columns
__global__ __launch_bounds__(256) void pair_kernel(
    const unsigned short* __restrict__ Xh, const float* __restrict__ sq,
    const int* __restrict__ labi, const float* __restrict__ marginp,
    float* __restrict__ accum, float* __restrict__ out)
{
  __shared__ char  Asl[SLAB * ROWB];     // 66,560 B -> 2 blocks/CU
  __shared__ float sRow[SLAB];
  __shared__ int   lRow[SLAB];
  __shared__ float rs1[4], rs2[4];
  __shared__ int   rc[4];

  int t = threadIdx.x;
  int bi = blockIdx.x >> 3;              // 64 row-slabs
  int jc = blockIdx.x & 7;               // 8 column chunks
  int rowbase = bi * SLAB;
  int colbase = jc * CHUNK;

  // ---- stage A slab once: coalesced 16B loads -> padded LDS rows
  {
    int r4 = t >> 6;                     // 0..3 (4 rows per pass)
    int ch = t & 63;                     // 16B chunk within a 1KB row
    #pragma unroll
    for (int p = 0; p < 16; ++p) {
      int row = p * 4 + r4;
      uint4 v = *(const uint4*)(Xh + (size_t)(rowbase + row) * DIM + ch * 8);
      *(uint4*)(Asl + row * ROWB + ch * 16) = v;
    }
  }
  if (t < SLAB) { sRow[t] = sq[rowbase + t]; lRow[t] = labi[rowbase + t]; }
  __syncthreads();                       // the ONLY staging barrier

  int wave = t >> 6, lane = t & 63;
  int quad = lane >> 4, ml = lane & 15;

  float margin = *marginp;
  float s1 = 0.f, s2 = 0.f;
  int cnt = 0;

  // each wave streams 8 j-tiles; straight-line unrolled body, no barriers
  for (int jt = wave; jt < NJT; jt += 4) {
    int jbase = colbase + jt * 16;
    const char* bbase = (const char*)(Xh + (size_t)(jbase + ml) * DIM + quad * 8);

    f32x4 acc0 = {}, acc1 = {}, acc2 = {}, acc3 = {};
    #pragma unroll
    for (int k = 0; k < 16; ++k) {
      f16x8 bf = *(const f16x8*)(bbase + k * 64);           // 16 full 64B lines, L2-hot
      const char* abase = Asl + k * 64 + quad * 16;
      f16x8 a0 = *(const f16x8*)(abase + (0 * 16 + ml) * ROWB);
      f16x8 a1 = *(const f16x8*)(abase + (1 * 16 + ml) * ROWB);
      f16x8 a2 = *(const f16x8*)(abase + (2 * 16 + ml) * ROWB);
      f16x8 a3 = *(const f16x8*)(abase + (3 * 16 + ml) * ROWB);
      acc0 = __builtin_amdgcn_mfma_f32_16x16x32_f16(a0, bf, acc0, 0, 0, 0);
      acc1 = __builtin_amdgcn_mfma_f32_16x16x32_f16(a1, bf, acc1, 0, 0, 0);
      acc2 = __builtin_amdgcn_mfma_f32_16x16x32_f16(a2, bf, acc2, 0, 0, 0);
      acc3 = __builtin_amdgcn_mfma_f32_16x16x32_f16(a3, bf, acc3, 0, 0, 0);
    }

    // fused loss for this j-tile; C/D: col=lane&15, row=(lane>>4)*4+reg
    float sqc = sq[jbase + ml];
    int   lc  = labi[jbase + ml];
    #pragma unroll
    for (int rt = 0; rt < 4; ++rt) {
      f32x4 a = (rt == 0) ? acc0 : (rt == 1) ? acc1 : (rt == 2) ? acc2 : acc3;
      int rbase = rt * 16 + quad * 4;
      #pragma unroll
      for (int i = 0; i < 4; ++i) {
        int row = rbase + i;
        float d = sRow[row] + sqc - 2.0f * a[i];
        d = fmaxf(d, 0.0f);
        if (lRow[row] == lc) { s1 += d; cnt++; }
        else                 { s2 += fmaxf(margin - d, 0.0f); }
      }
    }
  }

  // ---- block reduction + device accumulation
  #pragma unroll
  for (int off = 32; off; off >>= 1) {
    s1  += __shfl_down(s1, off, 64);
    s2  += __shfl_down(s2, off, 64);
    cnt += __shfl_down(cnt, off, 64);
  }
  if (lane == 0) { rs1[wave] = s1; rs2[wave] = s2; rc[wave] = cnt; }
  __syncthreads();
  if (t == 0) {
    float S1 = 0.f, S2 = 0.f;
    int C = 0;
    for (int w = 0; w < 4; ++w) { S1 += rs1[w]; S2 += rs2[w]; C += rc[w]; }
    atomicAdd(&accum[0], S1);
    atomicAdd(&accum[1], S2);
    atomicAdd((unsigned*)accum + 2, (unsigned)C);
    __threadfence();
    unsigned prev = atomicAdd((unsigned*)accum + 3, 1u);
    if (prev == GRID - 1) {
      float s1v = atomicAdd(&accum[0], 0.0f);
      float s2v = atomicAdd(&accum[1], 0.0f);
      unsigned c1 = atomicAdd((unsigned*)accum + 2, 0u);
      double zn1 = (double)c1;
      double zn2 = (double)NROWS * (double)NROWS - zn1;
      out[0] = (float)(0.5 * ((double)s1v / zn1 + (double)s2v / zn2));
    }
  }
}

extern "C" void kernel_launch(void* const* d_in, const int* in_sizes, int n_in,
                              void* d_out, int out_size, void* d_ws, size_t ws_size,
                              hipStream_t stream) {
  const float*     X      = (const float*)d_in[0];
  const long long* lab    = (const long long*)d_in[1];
  const float*     margin = (const float*)d_in[2];
  float*           out    = (float*)d_out;

  char* ws = (char*)d_ws;
  unsigned short* Xh   = (unsigned short*)(ws + OFF_XH);
  float*          sq   = (float*)(ws + OFF_SQ);
  int*            labi = (int*)(ws + OFF_LAB);
  unsigned*       accu = (unsigned*)(ws + OFF_ACC);

  prep_kernel<<<NROWS / 4, 256, 0, stream>>>(X, lab, Xh, sq, labi, accu);
  pair_kernel<<<GRID, 256, 0, stream>>>(Xh, sq, labi, margin, (float*)accu, out);
}